// Round 6
// baseline (1235.307 us; speedup 1.0000x reference)
//
#include <hip/hip_runtime.h>
#include <stdint.h>

#define T_STEPS 4
#define NTOK    8192
#define DMODEL  1024
#define NEXP    8
#define EFF     512
#define BMT     128                      // block tile rows (tokens); expert regions padded to 128
#define CAPTOT  (2*NTOK + NEXP*BMT)      // 17408 assignment slots incl. per-expert padding

typedef __attribute__((ext_vector_type(8))) short bf8_t;   // 8 bf16 (4 VGPRs) MFMA operand
typedef __attribute__((ext_vector_type(4))) float f32x4;   // MFMA accumulator

#define MFMA(a,b,c) __builtin_amdgcn_mfma_f32_16x16x32_bf16((a),(b),(c),0,0,0)

// LDS rows are 32 shorts (64B), no pad. 16B-chunk XOR swizzle:
// physical_chunk = logical_chunk ^ ((row>>1)&3). SQ_LDS_BANK_CONFLICT == 0 (r2-r5).
#define SWZC(r, c) ((((c) ^ (((r) >> 1) & 3))) * 8)   // short offset of 16B chunk

// async global->LDS DMA, 16B/lane, no VGPR round-trip (vmcnt-tracked)
typedef __attribute__((address_space(3))) unsigned int lds_uint;
typedef const __attribute__((address_space(1))) unsigned int glb_uint;
__device__ __forceinline__ void dma16(const void* g, void* l) {
    __builtin_amdgcn_global_load_lds((glb_uint*)g, (lds_uint*)l, 16, 0, 0);
}
#define S_BARRIER() __builtin_amdgcn_s_barrier()
#define SFENCE()    __builtin_amdgcn_sched_barrier(0)

// XCD-chunked swizzle: gridDim.x = 136 = 8*17, 136%8==0 so XCD = bx%8 regardless of
// blockIdx.y; give XCD k the contiguous m-range [17k,17k+17) ~= one expert region,
// so each XCD's 3MB expert weight slice stays resident in its private 4MB L2.
__device__ __forceinline__ int swz_mb(int bx) { return (bx & 7) * 17 + (bx >> 3); }

// ---------------- bf16 3-limb split helpers ----------------

__device__ __forceinline__ unsigned short bf16rn(float f) {
    unsigned u = __float_as_uint(f);
    unsigned r = u + 0x7fffu + ((u >> 16) & 1u);   // round-to-nearest-even
    return (unsigned short)(r >> 16);
}
__device__ __forceinline__ float bf2f(unsigned short h) {
    return __uint_as_float(((unsigned)h) << 16);
}
__device__ __forceinline__ unsigned pk(unsigned short a, unsigned short b) {
    return (unsigned)a | ((unsigned)b << 16);
}

// split 8 floats into 3 bf16 limbs, write 16B per limb
__device__ __forceinline__ void stage8_3limb(const float* __restrict__ src,
                                             unsigned short* d0, unsigned short* d1,
                                             unsigned short* d2) {
    float v[8];
    *(float4*)&v[0] = *(const float4*)(src + 0);
    *(float4*)&v[4] = *(const float4*)(src + 4);
    unsigned short h[8], m[8], l[8];
#pragma unroll
    for (int i = 0; i < 8; ++i) {
        unsigned short a = bf16rn(v[i]);
        float r1 = v[i] - bf2f(a);
        unsigned short b = bf16rn(r1);
        float r2 = r1 - bf2f(b);
        h[i] = a; m[i] = b; l[i] = bf16rn(r2);
    }
    *(uint4*)d0 = make_uint4(pk(h[0],h[1]), pk(h[2],h[3]), pk(h[4],h[5]), pk(h[6],h[7]));
    *(uint4*)d1 = make_uint4(pk(m[0],m[1]), pk(m[2],m[3]), pk(m[4],m[5]), pk(m[6],m[7]));
    *(uint4*)d2 = make_uint4(pk(l[0],l[1]), pk(l[2],l[3]), pk(l[4],l[5]), pk(l[6],l[7]));
}

// ---------------- limb pre-split (streaming; used for weights AND x) ----------------

__global__ void k_split(const float* __restrict__ w, unsigned short* __restrict__ h,
                        unsigned short* __restrict__ m, unsigned short* __restrict__ l) {
    size_t i = (size_t)(blockIdx.x * blockDim.x + threadIdx.x) * 8;
    stage8_3limb(w + i, h + i, m + i, l + i);
}

// ---------------- routing ----------------

__global__ void k_count(const int* __restrict__ idx, int* __restrict__ counts) {
    int n = blockIdx.x * blockDim.x + threadIdx.x;
    if (n >= NTOK) return;
    int e0 = idx[2*n], e1 = idx[2*n+1];
    atomicAdd(&counts[e0], 1);
    if (e1 != e0) atomicAdd(&counts[e1], 1);   // dedup duplicate top-k
}

__global__ void k_prefix(const int* __restrict__ counts, int* __restrict__ offsets) {
    if (threadIdx.x == 0) {
        int o = 0;
        for (int e = 0; e < NEXP; ++e) {
            offsets[e] = o;
            o += (counts[e] + BMT - 1) / BMT * BMT;   // pad each expert region to 128
        }
        offsets[NEXP] = o;
    }
}

__global__ void k_fill(const int* __restrict__ idx, const float* __restrict__ wts,
                       const int* __restrict__ offsets, int* __restrict__ cursors,
                       int* __restrict__ tok, float* __restrict__ wgt) {
    int n = blockIdx.x * blockDim.x + threadIdx.x;
    if (n >= NTOK) return;
    int e0 = idx[2*n], e1 = idx[2*n+1];
    float w0 = wts[2*n], w1 = wts[2*n+1];
    if (e0 == e1) w0 = __fadd_rn(w0, w1);      // reference scatter-add order
    int p0 = offsets[e0] + atomicAdd(&cursors[e0], 1);
    tok[p0] = n; wgt[p0] = w0;
    if (e1 != e0) {
        int p1 = offsets[e1] + atomicAdd(&cursors[e1], 1);
        tok[p1] = n; wgt[p1] = w1;
    }
}

// ---------------- up-proj (3-limb bf16 MFMA) + fused LIF -> bf16 spikes ----------------
// Block: 128 tokens x 128 features, K=1024 in 32-chunks. 4 waves, each 64x64 (4x4 tiles).
// ALL operands pre-split in global -> pure DMA staging, ZERO split VALU, zero staging
// VGPRs (r5 lesson: VALU-split was the pinned 33% VALUBusy; r4 lesson: no VGPR headroom).
// B double-buffered prefetch (in flight across barriers, vmcnt(6)); A single-buffered,
// DMA'd in-step (mostly L2-latency thanks to XCD swizzle; overlapped by co-resident block).

__global__ __launch_bounds__(256, 2)
void k_up(const unsigned short* __restrict__ xh, const unsigned short* __restrict__ xm,
          const unsigned short* __restrict__ xl,
          const unsigned short* __restrict__ uwh, const unsigned short* __restrict__ uwm,
          const unsigned short* __restrict__ uwl,
          const int* __restrict__ offsets, const int* __restrict__ tok,
          unsigned short* __restrict__ spk) {
    const int m0 = swz_mb(blockIdx.x) * BMT;
    const int ft = blockIdx.y;
    if (m0 >= offsets[NEXP]) return;
    int e = 0;
    for (int i = 1; i < NEXP; ++i) if (m0 >= offsets[i]) e = i;

    __shared__ __align__(16) unsigned short As[3][128][32];      // 24 KB, single-buffered
    __shared__ __align__(16) unsigned short Bs[2][3][128][32];   // 48 KB, double-buffered
    // total 72 KB -> 2 blocks/CU

    const int tid  = threadIdx.x;
    const int lane = tid & 63, wid = tid >> 6;
    const int quad = lane >> 4, l16 = lane & 15;
    const int mw = (wid & 1) * 64, nw = (wid >> 1) * 64;

    // DMA lane roles: lane l -> row base+(l>>2), phys chunk l&3; source fetches logical
    // chunk (l&3)^((l>>3)&3) so LDS (linear dest) ends up SWZC-swizzled.
    const int drow  = lane >> 2;
    const int dclog = (lane & 3) ^ ((lane >> 3) & 3);
    const unsigned short* wlimb[3] = { uwh, uwm, uwl };
    const unsigned short* xlimb[3] = { xh, xm, xl };
    const size_t wrow0 = ((size_t)e * EFF + ft * 128) * DMODEL;
    const int tok0 = tok[m0 + wid*16 + drow];         // token for A rows [wid*16+drow]
    const int tok1 = tok[m0 + 64 + wid*16 + drow];    // and +64 half

    // frag-read k-chunk (uniform across mt/nt)
    const int kq = SWZC(l16, quad);

    f32x4 mem[4][4];
#pragma unroll
    for (int i = 0; i < 4; ++i)
#pragma unroll
        for (int j = 0; j < 4; ++j) mem[i][j] = (f32x4){0.f,0.f,0.f,0.f};

    // prologue: DMA B(step 0) into Bs[0]
#pragma unroll
    for (int j = 0; j < 6; ++j) {
        const int limb = j >> 1, rh = j & 1;
        dma16(wlimb[limb] + wrow0 + (size_t)(rh*64 + wid*16 + drow) * DMODEL + dclog*8,
              &Bs[0][limb][rh*64 + wid*16][0]);
    }

    int cur = 0;
    for (int t = 0; t < T_STEPS; ++t) {
        f32x4 acc[4][4];
#pragma unroll
        for (int i = 0; i < 4; ++i)
#pragma unroll
            for (int j = 0; j < 4; ++j) acc[i][j] = (f32x4){0.f,0.f,0.f,0.f};

        for (int kc = 0; kc < DMODEL; kc += 32) {
            const bool last = (t == T_STEPS - 1) && (kc == DMODEL - 32);
            // (W): all waves done reading As(prev) / Bs[cur^1](prev)
            asm volatile("s_waitcnt lgkmcnt(0)" ::: "memory");
            SFENCE();
            S_BARRIER();
            SFENCE();
            // A DMA for CURRENT step (single-buffered; dest just freed by (W))
#pragma unroll
            for (int j = 0; j < 6; ++j) {
                const int limb = j >> 1, rh = j & 1;
                const int tk = rh ? tok1 : tok0;
                dma16(xlimb[limb] + ((size_t)t * NTOK + tk) * DMODEL + kc + dclog*8,
                      &As[limb][rh*64 + wid*16][0]);
            }
            // B DMA for NEXT step (stays in flight across the whole step)
            if (!last) {
                const int nkk = (kc == DMODEL - 32) ? 0 : kc + 32;   // B is t-independent
#pragma unroll
                for (int j = 0; j < 6; ++j) {
                    const int limb = j >> 1, rh = j & 1;
                    dma16(wlimb[limb] + wrow0 + (size_t)(rh*64 + wid*16 + drow) * DMODEL
                              + nkk + dclog*8,
                          &Bs[cur ^ 1][limb][rh*64 + wid*16][0]);
                }
                // A(cur)+B(cur) done when <=6 newer (next-B) outstanding
                asm volatile("s_waitcnt vmcnt(6)" ::: "memory");
            } else {
                asm volatile("s_waitcnt vmcnt(0)" ::: "memory");
            }
            SFENCE();
            S_BARRIER();   // (R): every wave passed its counted wait -> As + Bs[cur] ready
            SFENCE();

            bf8_t bh[4], bm[4], bl[4];
#pragma unroll
            for (int nt = 0; nt < 4; ++nt) {
                const int nr = nw + nt*16 + l16;
                bh[nt] = *(const bf8_t*)&Bs[cur][0][nr][kq];
                bm[nt] = *(const bf8_t*)&Bs[cur][1][nr][kq];
                bl[nt] = *(const bf8_t*)&Bs[cur][2][nr][kq];
            }
#pragma unroll
            for (int mt = 0; mt < 4; ++mt) {
                const int mr = mw + mt*16 + l16;
                bf8_t ah = *(const bf8_t*)&As[0][mr][kq];
                bf8_t am = *(const bf8_t*)&As[1][mr][kq];
                bf8_t al = *(const bf8_t*)&As[2][mr][kq];
#pragma unroll
                for (int nt = 0; nt < 4; ++nt) {
                    f32x4 c = acc[mt][nt];
                    c = MFMA(ah, bh[nt], c);
                    c = MFMA(am, bh[nt], c);
                    c = MFMA(ah, bm[nt], c);
                    c = MFMA(am, bm[nt], c);
                    c = MFMA(al, bh[nt], c);
                    c = MFMA(ah, bl[nt], c);
                    acc[mt][nt] = c;
                }
            }
            cur ^= 1;
        }

        // fused LIF epilogue (C layout: row = quad*4+reg, col = l16)
#pragma unroll
        for (int mt = 0; mt < 4; ++mt)
#pragma unroll
            for (int nt = 0; nt < 4; ++nt)
#pragma unroll
                for (int reg = 0; reg < 4; ++reg) {
                    float mv = __fadd_rn(__fmul_rn(0.9f, mem[mt][nt][reg]), acc[mt][nt][reg]);
                    bool s = mv > 1.0f;
                    mem[mt][nt][reg] = __fsub_rn(mv, s ? 1.0f : 0.0f);
                    int row = m0 + mw + mt*16 + quad*4 + reg;
                    int col = ft*128 + nw + nt*16 + l16;
                    spk[((size_t)t * CAPTOT + row) * EFF + col] = s ? 0x3F80u : 0u;
                }
    }
}

// ---------------- down-proj (spikes exact bf16 x pre-split 3-limb weights) + fused LIF + scatter ----------------
// Block: 128 tokens x 128 d_model cols, K=512 in 32-chunks. 4 waves, each 64x64 (4x4 tiles).
// Both operands DMA'd, double-buffered; counted vmcnt(8). XCD swizzle keeps the 3MB
// expert B slice L2-resident (it was re-fetched 4x = ~1.7GB before).

__global__ __launch_bounds__(256, 2)
void k_dn(const unsigned short* __restrict__ spk,
          const unsigned short* __restrict__ dwh, const unsigned short* __restrict__ dwm,
          const unsigned short* __restrict__ dwl,
          const int* __restrict__ offsets, const int* __restrict__ tok,
          const float* __restrict__ wgt, float* __restrict__ out) {
    const int m0 = swz_mb(blockIdx.x) * BMT;
    const int dt = blockIdx.y;
    if (m0 >= offsets[NEXP]) return;
    int e = 0;
    for (int i = 1; i < NEXP; ++i) if (m0 >= offsets[i]) e = i;

    __shared__ __align__(16) unsigned short As[2][128][32];      // 16 KB
    __shared__ __align__(16) unsigned short Bs[2][3][128][32];   // 48 KB

    const int tid  = threadIdx.x;
    const int lane = tid & 63, wid = tid >> 6;
    const int quad = lane >> 4, l16 = lane & 15;
    const int mw = (wid & 1) * 64, nw = (wid >> 1) * 64;

    const unsigned short* dlimb[3] = { dwh, dwm, dwl };
    const size_t drow0 = ((size_t)e * DMODEL + dt * 128) * EFF;
    const int drow  = lane >> 2;
    const int dclog = (lane & 3) ^ ((lane >> 3) & 3);

    const int kq = SWZC(l16, quad);

    f32x4 mem[4][4];
#pragma unroll
    for (int i = 0; i < 4; ++i)
#pragma unroll
        for (int j = 0; j < 4; ++j) mem[i][j] = (f32x4){0.f,0.f,0.f,0.f};

    // prologue: DMA A(0,0) + B(0) into buffer 0
#pragma unroll
    for (int j2 = 0; j2 < 2; ++j2) {
        const int row = j2*64 + wid*16 + drow;
        dma16(spk + ((size_t)0 * CAPTOT + m0 + row) * EFF + dclog*8,
              &As[0][j2*64 + wid*16][0]);
    }
#pragma unroll
    for (int j = 0; j < 6; ++j) {
        const int limb = j >> 1, rh = j & 1;
        dma16(dlimb[limb] + drow0 + (size_t)(rh*64 + wid*16 + drow) * EFF + dclog*8,
              &Bs[0][limb][rh*64 + wid*16][0]);
    }

    int cur = 0;
    for (int t = 0; t < T_STEPS; ++t) {
        f32x4 acc[4][4];
#pragma unroll
        for (int i = 0; i < 4; ++i)
#pragma unroll
            for (int j = 0; j < 4; ++j) acc[i][j] = (f32x4){0.f,0.f,0.f,0.f};

        for (int kc = 0; kc < EFF; kc += 32) {
            const bool last = (t == T_STEPS - 1) && (kc == EFF - 32);
            asm volatile("s_waitcnt lgkmcnt(0)" ::: "memory");
            SFENCE();
            S_BARRIER();
            SFENCE();
            if (!last) {
                int ntt = t, nkk = kc + 32;
                if (nkk == EFF) { nkk = 0; ntt = t + 1; }
#pragma unroll
                for (int j2 = 0; j2 < 2; ++j2) {
                    const int row = j2*64 + wid*16 + drow;
                    dma16(spk + ((size_t)ntt * CAPTOT + m0 + row) * EFF + nkk + dclog*8,
                          &As[cur ^ 1][j2*64 + wid*16][0]);
                }
#pragma unroll
                for (int j = 0; j < 6; ++j) {
                    const int limb = j >> 1, rh = j & 1;
                    dma16(dlimb[limb] + drow0 + (size_t)(rh*64 + wid*16 + drow) * EFF
                              + nkk + dclog*8,
                          &Bs[cur ^ 1][limb][rh*64 + wid*16][0]);
                }
                asm volatile("s_waitcnt vmcnt(8)" ::: "memory");
            } else {
                asm volatile("s_waitcnt vmcnt(0)" ::: "memory");
            }
            SFENCE();
            S_BARRIER();   // (R)
            SFENCE();

            bf8_t bh[4], bm[4], bl[4];
#pragma unroll
            for (int nt = 0; nt < 4; ++nt) {
                const int nr = nw + nt*16 + l16;
                bh[nt] = *(const bf8_t*)&Bs[cur][0][nr][kq];
                bm[nt] = *(const bf8_t*)&Bs[cur][1][nr][kq];
                bl[nt] = *(const bf8_t*)&Bs[cur][2][nr][kq];
            }
#pragma unroll
            for (int mt = 0; mt < 4; ++mt) {
                const int mr = mw + mt*16 + l16;
                bf8_t a = *(const bf8_t*)&As[cur][mr][kq];
#pragma unroll
                for (int nt = 0; nt < 4; ++nt) {
                    f32x4 c = acc[mt][nt];
                    c = MFMA(a, bh[nt], c);
                    c = MFMA(a, bm[nt], c);
                    c = MFMA(a, bl[nt], c);
                    acc[mt][nt] = c;
                }
            }
            cur ^= 1;
        }

        // fused LIF + weighted sparse scatter
#pragma unroll
        for (int mt = 0; mt < 4; ++mt) {
            const int rbase = m0 + mw + mt*16 + quad*4;
#pragma unroll
            for (int reg = 0; reg < 4; ++reg) {
                const int   n = tok[rbase + reg];
                const float w = wgt[rbase + reg];
#pragma unroll
                for (int nt = 0; nt < 4; ++nt) {
                    float mv = __fadd_rn(__fmul_rn(0.9f, mem[mt][nt][reg]), acc[mt][nt][reg]);
                    bool s = mv > 1.0f;
                    mem[mt][nt][reg] = __fsub_rn(mv, s ? 1.0f : 0.0f);
                    if (s && w != 0.0f) {
                        int col = dt*128 + nw + nt*16 + l16;
                        atomicAdd(out + ((size_t)t * NTOK + n) * DMODEL + col, w);
                    }
                }
            }
        }
    }
}

// ---------------- launch ----------------

extern "C" void kernel_launch(void* const* d_in, const int* in_sizes, int n_in,
                              void* d_out, int out_size, void* d_ws, size_t ws_size,
                              hipStream_t stream) {
    const float* x      = (const float*)d_in[0];
    const int*   idx    = (const int*)  d_in[1];
    const float* wts    = (const float*)d_in[2];
    const float* up_w   = (const float*)d_in[3];
    const float* down_w = (const float*)d_in[4];
    float* out = (float*)d_out;

    char* ws = (char*)d_ws;
    int*   counts  = (int*)(ws + 0);
    int*   cursors = (int*)(ws + 32);
    int*   offsets = (int*)(ws + 64);
    int*   tok     = (int*)(ws + 128);
    float* wgt     = (float*)(ws + 128 + (size_t)CAPTOT * 4);
    unsigned short* spk = (unsigned short*)(ws + 128 + (size_t)CAPTOT * 8);

    const size_t WSPK = (size_t)T_STEPS * CAPTOT * EFF * 2;             // 71.3 MB
    size_t base2 = 128 + (size_t)CAPTOT * 8 + WSPK;
    base2 = (base2 + 511) & ~(size_t)511;
    const size_t WLIMB = (size_t)NEXP * EFF * DMODEL * 2;               // 8.39 MB per limb
    unsigned short* uwh = (unsigned short*)(ws + base2);
    unsigned short* uwm = (unsigned short*)(ws + base2 + 1*WLIMB);
    unsigned short* uwl = (unsigned short*)(ws + base2 + 2*WLIMB);
    unsigned short* dwh = (unsigned short*)(ws + base2 + 3*WLIMB);
    unsigned short* dwm = (unsigned short*)(ws + base2 + 4*WLIMB);
    unsigned short* dwl = (unsigned short*)(ws + base2 + 5*WLIMB);
    size_t base3 = base2 + 6*WLIMB;
    const size_t XLIMB = (size_t)T_STEPS * NTOK * DMODEL * 2;           // 64 MB per limb
    unsigned short* xh = (unsigned short*)(ws + base3);
    unsigned short* xm = (unsigned short*)(ws + base3 + 1*XLIMB);
    unsigned short* xl = (unsigned short*)(ws + base3 + 2*XLIMB);
    // total ws: ~315 MB

    hipMemsetAsync(ws, 0, 128 + (size_t)CAPTOT * 8, stream);
    hipMemsetAsync(out, 0, (size_t)out_size * sizeof(float), stream);

    // limb pre-splits: weights (one-shot cheap) + x (streaming, ~330MB traffic)
    const int nsplit = NEXP * EFF * DMODEL / 8 / 256;                   // 2048
    k_split<<<nsplit, 256, 0, stream>>>(up_w,   uwh, uwm, uwl);
    k_split<<<nsplit, 256, 0, stream>>>(down_w, dwh, dwm, dwl);
    const int nsplitx = T_STEPS * NTOK * DMODEL / 8 / 256;              // 16384
    k_split<<<nsplitx, 256, 0, stream>>>(x, xh, xm, xl);

    k_count <<<(NTOK + 255) / 256, 256, 0, stream>>>(idx, counts);
    k_prefix<<<1, 64, 0, stream>>>(counts, offsets);
    k_fill  <<<(NTOK + 255) / 256, 256, 0, stream>>>(idx, wts, offsets, cursors, tok, wgt);

    dim3 gup(CAPTOT / BMT, EFF / 128);      // (136, 4); tiles past used rows early-exit
    k_up<<<gup, 256, 0, stream>>>(xh, xm, xl, uwh, uwm, uwl, offsets, tok, spk);

    dim3 gdn(CAPTOT / BMT, DMODEL / 128);   // (136, 8)
    k_dn<<<gdn, 256, 0, stream>>>(spk, dwh, dwm, dwl, offsets, tok, wgt, out);
}

// Round 7
// 1192.129 us; speedup vs baseline: 1.0362x; 1.0362x over previous
//
#include <hip/hip_runtime.h>
#include <stdint.h>

#define T_STEPS 4
#define NTOK    8192
#define DMODEL  1024
#define NEXP    8
#define EFF     512
#define BMT     128                      // block tile rows (tokens); expert regions padded to 128
#define CAPTOT  (2*NTOK + NEXP*BMT)      // 17408 assignment slots incl. per-expert padding

typedef __attribute__((ext_vector_type(8))) short bf8_t;   // 8 bf16 (4 VGPRs) MFMA operand
typedef __attribute__((ext_vector_type(4))) float f32x4;   // MFMA accumulator

#define MFMA(a,b,c) __builtin_amdgcn_mfma_f32_16x16x32_bf16((a),(b),(c),0,0,0)

// 32-short (64B) LDS rows: phys_chunk = logical_chunk ^ ((row>>1)&3). Conflict-free (r2-r5).
#define SWZC(r, c)  ((((c) ^ (((r) >> 1) & 3))) * 8)
// 64-short (128B) LDS rows: phys_chunk = logical_chunk ^ (row&7). Reads 2-way (free, m136).
#define SWZ64(r, c) ((((c) ^ ((r) & 7))) * 8)

// async global->LDS DMA, 16B/lane, no VGPR round-trip (vmcnt-tracked)
typedef __attribute__((address_space(3))) unsigned int lds_uint;
typedef const __attribute__((address_space(1))) unsigned int glb_uint;
__device__ __forceinline__ void dma16(const void* g, void* l) {
    __builtin_amdgcn_global_load_lds((glb_uint*)g, (lds_uint*)l, 16, 0, 0);
}
#define S_BARRIER() __builtin_amdgcn_s_barrier()
#define SFENCE()    __builtin_amdgcn_sched_barrier(0)

// XCD-chunked swizzle: gridDim.x = 136 = 8*17 (136%8==0 so XCD = bx%8 for any blockIdx.y);
// XCD k owns contiguous m-range ~ one expert region -> 3MB weight slice L2-resident.
// Measured r6: FETCH 625->430MB.
__device__ __forceinline__ int swz_mb(int bx) { return (bx & 7) * 17 + (bx >> 3); }

// ---------------- bf16 3-limb split helpers ----------------

__device__ __forceinline__ unsigned short bf16rn(float f) {
    unsigned u = __float_as_uint(f);
    unsigned r = u + 0x7fffu + ((u >> 16) & 1u);   // round-to-nearest-even
    return (unsigned short)(r >> 16);
}
__device__ __forceinline__ float bf2f(unsigned short h) {
    return __uint_as_float(((unsigned)h) << 16);
}
__device__ __forceinline__ unsigned pk(unsigned short a, unsigned short b) {
    return (unsigned)a | ((unsigned)b << 16);
}

// split 8 floats (in regs) into 3 bf16 limbs, write 16B per limb to LDS
__device__ __forceinline__ void split8v(float4 va, float4 vb,
                                        unsigned short* d0, unsigned short* d1,
                                        unsigned short* d2) {
    float v[8];
    *(float4*)&v[0] = va;
    *(float4*)&v[4] = vb;
    unsigned short h[8], m[8], l[8];
#pragma unroll
    for (int i = 0; i < 8; ++i) {
        unsigned short a = bf16rn(v[i]);
        float r1 = v[i] - bf2f(a);
        unsigned short b = bf16rn(r1);
        float r2 = r1 - bf2f(b);
        h[i] = a; m[i] = b; l[i] = bf16rn(r2);
    }
    *(uint4*)d0 = make_uint4(pk(h[0],h[1]), pk(h[2],h[3]), pk(h[4],h[5]), pk(h[6],h[7]));
    *(uint4*)d1 = make_uint4(pk(m[0],m[1]), pk(m[2],m[3]), pk(m[4],m[5]), pk(m[6],m[7]));
    *(uint4*)d2 = make_uint4(pk(l[0],l[1]), pk(l[2],l[3]), pk(l[4],l[5]), pk(l[6],l[7]));
}

__device__ __forceinline__ void stage8_3limb(const float* __restrict__ src,
                                             unsigned short* d0, unsigned short* d1,
                                             unsigned short* d2) {
    float4 va = *(const float4*)(src + 0);
    float4 vb = *(const float4*)(src + 4);
    split8v(va, vb, d0, d1, d2);
}

// ---------------- weight limb pre-split (one-shot, streaming) ----------------

__global__ void k_split(const float* __restrict__ w, unsigned short* __restrict__ h,
                        unsigned short* __restrict__ m, unsigned short* __restrict__ l) {
    size_t i = (size_t)(blockIdx.x * blockDim.x + threadIdx.x) * 8;
    stage8_3limb(w + i, h + i, m + i, l + i);
}

// ---------------- routing ----------------

__global__ void k_count(const int* __restrict__ idx, int* __restrict__ counts) {
    int n = blockIdx.x * blockDim.x + threadIdx.x;
    if (n >= NTOK) return;
    int e0 = idx[2*n], e1 = idx[2*n+1];
    atomicAdd(&counts[e0], 1);
    if (e1 != e0) atomicAdd(&counts[e1], 1);   // dedup duplicate top-k
}

__global__ void k_prefix(const int* __restrict__ counts, int* __restrict__ offsets) {
    if (threadIdx.x == 0) {
        int o = 0;
        for (int e = 0; e < NEXP; ++e) {
            offsets[e] = o;
            o += (counts[e] + BMT - 1) / BMT * BMT;   // pad each expert region to 128
        }
        offsets[NEXP] = o;
    }
}

__global__ void k_fill(const int* __restrict__ idx, const float* __restrict__ wts,
                       const int* __restrict__ offsets, int* __restrict__ cursors,
                       int* __restrict__ tok, float* __restrict__ wgt) {
    int n = blockIdx.x * blockDim.x + threadIdx.x;
    if (n >= NTOK) return;
    int e0 = idx[2*n], e1 = idx[2*n+1];
    float w0 = wts[2*n], w1 = wts[2*n+1];
    if (e0 == e1) w0 = __fadd_rn(w0, w1);      // reference scatter-add order
    int p0 = offsets[e0] + atomicAdd(&cursors[e0], 1);
    tok[p0] = n; wgt[p0] = w0;
    if (e1 != e0) {
        int p1 = offsets[e1] + atomicAdd(&cursors[e1], 1);
        tok[p1] = n; wgt[p1] = w1;
    }
}

// ---------------- up-proj (3-limb bf16 MFMA) + fused LIF -> bf16 spikes ----------------
// r5-proven structure (428us): A = f32 reg-prefetch one step ahead + in-kernel limb split
// (the split VALU overlaps the pipeline bubble -- r5/r6 comparison proved it is NOT the
// critical path); B = pre-split limbs DMA'd into double-buffered LDS, in flight across
// barriers with counted vmcnt(10). r6 lesson: do NOT DMA A in-step (single-buffered As
// forces issue+wait within one step -> +1200 cyc/step). Added this round: XCD swizzle
// (FETCH 625->430MB measured) + s_setprio around the MFMA cluster.

__global__ __launch_bounds__(256, 2)
void k_up(const float* __restrict__ x,
          const unsigned short* __restrict__ uwh, const unsigned short* __restrict__ uwm,
          const unsigned short* __restrict__ uwl,
          const int* __restrict__ offsets, const int* __restrict__ tok,
          unsigned short* __restrict__ spk) {
    const int m0 = swz_mb(blockIdx.x) * BMT;
    const int ft = blockIdx.y;
    if (m0 >= offsets[NEXP]) return;
    int e = 0;
    for (int i = 1; i < NEXP; ++i) if (m0 >= offsets[i]) e = i;

    __shared__ __align__(16) unsigned short As[3][128][32];      // 24 KB, single-buffered
    __shared__ __align__(16) unsigned short Bs[2][3][128][32];   // 48 KB, double-buffered
    // total 72 KB -> 2 blocks/CU

    const int tid  = threadIdx.x;
    const int lane = tid & 63, wid = tid >> 6;
    const int quad = lane >> 4, l16 = lane & 15;
    const int mw = (wid & 1) * 64, nw = (wid >> 1) * 64;

    // A staging roles: thread -> row r (0..127), 16-elem half
    const int r = tid >> 1, half = tid & 1;
    const int c0 = SWZC(r, half*2 + 0);
    const int c1 = SWZC(r, half*2 + 1);
    const int tokA = tok[m0 + r];
    const float* xbase = x + (size_t)tokA * DMODEL + half * 16;

    // B DMA roles: lane l -> row rh*64+wid*16+(l>>2), phys chunk l&3; source fetches
    // logical chunk (l&3)^((l>>3)&3) so linear LDS dest ends up SWZC-swizzled.
    const unsigned short* wlimb[3] = { uwh, uwm, uwl };
    const size_t wrow0 = ((size_t)e * EFF + ft * 128) * DMODEL;
    const int drow  = lane >> 2;
    const int dclog = (lane & 3) ^ ((lane >> 3) & 3);

    // frag-read k-chunk (uniform across mt/nt)
    const int kq = SWZC(l16, quad);

    f32x4 mem[4][4];
#pragma unroll
    for (int i = 0; i < 4; ++i)
#pragma unroll
        for (int j = 0; j < 4; ++j) mem[i][j] = (f32x4){0.f,0.f,0.f,0.f};

    // prologue: DMA B(step 0) into Bs[0]; load A(step 0) into regs
#pragma unroll
    for (int j = 0; j < 6; ++j) {
        const int limb = j >> 1, rh = j & 1;
        dma16(wlimb[limb] + wrow0 + (size_t)(rh*64 + wid*16 + drow) * DMODEL + dclog*8,
              &Bs[0][limb][rh*64 + wid*16][0]);
    }
    float4 pa[4];
#pragma unroll
    for (int i = 0; i < 4; ++i) pa[i] = ((const float4*)xbase)[i];

    int cur = 0;
    for (int t = 0; t < T_STEPS; ++t) {
        f32x4 acc[4][4];
#pragma unroll
        for (int i = 0; i < 4; ++i)
#pragma unroll
            for (int j = 0; j < 4; ++j) acc[i][j] = (f32x4){0.f,0.f,0.f,0.f};

        const float* xrow = xbase + (size_t)t * NTOK * DMODEL;

        for (int kc = 0; kc < DMODEL; kc += 32) {
            const bool last = (t == T_STEPS - 1) && (kc == DMODEL - 32);
            // (W): all waves done reading As / Bs[cur^1]
            asm volatile("s_waitcnt lgkmcnt(0)" ::: "memory");
            SFENCE();
            S_BARRIER();
            SFENCE();
            // next-step B DMA into the freed buffer (stays in flight all step)
            if (!last) {
                const int nkk = (kc == DMODEL - 32) ? 0 : kc + 32;   // B is t-independent
#pragma unroll
                for (int j = 0; j < 6; ++j) {
                    const int limb = j >> 1, rh = j & 1;
                    dma16(wlimb[limb] + wrow0 + (size_t)(rh*64 + wid*16 + drow) * DMODEL
                              + nkk + dclog*8,
                          &Bs[cur ^ 1][limb][rh*64 + wid*16][0]);
                }
            }
            // stage A (consumes pa; DMAs stay in flight)
            split8v(pa[0], pa[1], &As[0][r][c0], &As[1][r][c0], &As[2][r][c0]);
            split8v(pa[2], pa[3], &As[0][r][c1], &As[1][r][c1], &As[2][r][c1]);
            // issue next-step A loads
            if (!last) {
                const float* nxtA = (kc == DMODEL - 32)
                    ? xbase + (size_t)(t + 1) * NTOK * DMODEL
                    : xrow + kc + 32;
#pragma unroll
                for (int i = 0; i < 4; ++i) pa[i] = ((const float4*)nxtA)[i];
                // B(cur) done when <=10 newer ops (6 B-DMA + 4 A-loads) outstanding
                asm volatile("s_waitcnt vmcnt(10) lgkmcnt(0)" ::: "memory");
            } else {
                asm volatile("s_waitcnt vmcnt(0) lgkmcnt(0)" ::: "memory");
            }
            SFENCE();
            S_BARRIER();   // (R): every wave passed its counted wait -> B(cur)+As ready
            SFENCE();

            bf8_t bh[4], bm[4], bl[4];
#pragma unroll
            for (int nt = 0; nt < 4; ++nt) {
                const int nr = nw + nt*16 + l16;
                bh[nt] = *(const bf8_t*)&Bs[cur][0][nr][kq];
                bm[nt] = *(const bf8_t*)&Bs[cur][1][nr][kq];
                bl[nt] = *(const bf8_t*)&Bs[cur][2][nr][kq];
            }
            __builtin_amdgcn_s_setprio(1);
#pragma unroll
            for (int mt = 0; mt < 4; ++mt) {
                const int mr = mw + mt*16 + l16;
                bf8_t ah = *(const bf8_t*)&As[0][mr][kq];
                bf8_t am = *(const bf8_t*)&As[1][mr][kq];
                bf8_t al = *(const bf8_t*)&As[2][mr][kq];
#pragma unroll
                for (int nt = 0; nt < 4; ++nt) {
                    f32x4 c = acc[mt][nt];
                    c = MFMA(ah, bh[nt], c);
                    c = MFMA(am, bh[nt], c);
                    c = MFMA(ah, bm[nt], c);
                    c = MFMA(am, bm[nt], c);
                    c = MFMA(al, bh[nt], c);
                    c = MFMA(ah, bl[nt], c);
                    acc[mt][nt] = c;
                }
            }
            __builtin_amdgcn_s_setprio(0);
            cur ^= 1;
        }

        // fused LIF epilogue (C layout: row = quad*4+reg, col = l16)
#pragma unroll
        for (int mt = 0; mt < 4; ++mt)
#pragma unroll
            for (int nt = 0; nt < 4; ++nt)
#pragma unroll
                for (int reg = 0; reg < 4; ++reg) {
                    float mv = __fadd_rn(__fmul_rn(0.9f, mem[mt][nt][reg]), acc[mt][nt][reg]);
                    bool s = mv > 1.0f;
                    mem[mt][nt][reg] = __fsub_rn(mv, s ? 1.0f : 0.0f);
                    int row = m0 + mw + mt*16 + quad*4 + reg;
                    int col = ft*128 + nw + nt*16 + l16;
                    spk[((size_t)t * CAPTOT + row) * EFF + col] = s ? 0x3F80u : 0u;
                }
    }
}

// ---------------- down-proj (spikes x pre-split 3-limb weights) + fused LIF + scatter ----------------
// Restructured: BK=64 -> 32 barrier-pairs per block (was 64), 96 MFMA/wave/step (was 48).
// As double-buffered (spikes; HBM stream, prefetched 1 step ahead, latency hidden);
// Bs single-buffered, DMA'd in-step -- safe because the 3MB expert slice is L2-resident
// under the XCD swizzle (~300cy exposure). 80KB LDS = exactly 2 blocks/CU.
// K-chunk and per-chunk limb MFMA order identical to before -> bit-exact.

__global__ __launch_bounds__(256, 2)
void k_dn(const unsigned short* __restrict__ spk,
          const unsigned short* __restrict__ dwh, const unsigned short* __restrict__ dwm,
          const unsigned short* __restrict__ dwl,
          const int* __restrict__ offsets, const int* __restrict__ tok,
          const float* __restrict__ wgt, float* __restrict__ out) {
    const int m0 = swz_mb(blockIdx.x) * BMT;
    const int dt = blockIdx.y;
    if (m0 >= offsets[NEXP]) return;
    int e = 0;
    for (int i = 1; i < NEXP; ++i) if (m0 >= offsets[i]) e = i;

    __shared__ __align__(16) unsigned short As[2][128][64];   // 32 KB spikes, double-buffered
    __shared__ __align__(16) unsigned short Bs[3][128][64];   // 48 KB weights, single-buffered

    const int tid  = threadIdx.x;
    const int lane = tid & 63, wid = tid >> 6;
    const int quad = lane >> 4, l16 = lane & 15;
    const int mw = (wid & 1) * 64, nw = (wid >> 1) * 64;

    const unsigned short* dlimb[3] = { dwh, dwm, dwl };
    const size_t drow0 = ((size_t)e * DMODEL + dt * 128) * EFF;
    // DMA roles (128B rows): one dma16 = 1024B = 8 rows; lane l -> row +(l>>3),
    // phys chunk l&7; source logical chunk (l&7)^((l>>3)&7) -> SWZ64 layout in LDS.
    const int drow8 = lane >> 3;
    const int dclog = (lane & 7) ^ ((lane >> 3) & 7);

    f32x4 mem[4][4];
#pragma unroll
    for (int i = 0; i < 4; ++i)
#pragma unroll
        for (int j = 0; j < 4; ++j) mem[i][j] = (f32x4){0.f,0.f,0.f,0.f};

    // prologue: A(step 0) prefetch; rows wave-partitioned (wave w: rows w*32..w*32+31)
#pragma unroll
    for (int j2 = 0; j2 < 4; ++j2) {
        const int rowb = wid*32 + j2*8;
        dma16(spk + ((size_t)(m0 + rowb + drow8)) * EFF + dclog*8,
              &As[0][rowb][0]);
    }

    int cur = 0;
    for (int t = 0; t < T_STEPS; ++t) {
        f32x4 acc[4][4];
#pragma unroll
        for (int i = 0; i < 4; ++i)
#pragma unroll
            for (int j = 0; j < 4; ++j) acc[i][j] = (f32x4){0.f,0.f,0.f,0.f};

        for (int kc = 0; kc < EFF; kc += 64) {
            const bool last = (t == T_STEPS - 1) && (kc == EFF - 64);
            // (W): all waves done reading Bs(prev) and As[cur^1](prev step)
            asm volatile("s_waitcnt lgkmcnt(0)" ::: "memory");
            SFENCE();
            S_BARRIER();
            SFENCE();
            // B(this step): in-step DMA, L2-resident (12 issues/wave)
#pragma unroll
            for (int limb = 0; limb < 3; ++limb)
#pragma unroll
                for (int j2 = 0; j2 < 4; ++j2) {
                    const int rowb = wid*32 + j2*8;
                    dma16(dlimb[limb] + drow0 + (size_t)(rowb + drow8) * EFF + kc + dclog*8,
                          &Bs[limb][rowb][0]);
                }
            // A(next step) prefetch into the freed buffer (4 issues/wave)
            if (!last) {
                int ntt = t, nkk = kc + 64;
                if (nkk == EFF) { nkk = 0; ntt = t + 1; }
#pragma unroll
                for (int j2 = 0; j2 < 4; ++j2) {
                    const int rowb = wid*32 + j2*8;
                    dma16(spk + ((size_t)ntt * CAPTOT + m0 + rowb + drow8) * EFF + nkk + dclog*8,
                          &As[cur ^ 1][rowb][0]);
                }
                // A(cur)+B(cur) done when <=4 newer (next-A) outstanding
                asm volatile("s_waitcnt vmcnt(4)" ::: "memory");
            } else {
                asm volatile("s_waitcnt vmcnt(0)" ::: "memory");
            }
            SFENCE();
            S_BARRIER();   // (R)
            SFENCE();

            __builtin_amdgcn_s_setprio(1);
#pragma unroll
            for (int kk = 0; kk < 2; ++kk) {
                bf8_t bh[4], bm[4], bl[4];
#pragma unroll
                for (int nt = 0; nt < 4; ++nt) {
                    const int nr = nw + nt*16 + l16;
                    const int kb = SWZ64(nr, quad + kk*4);
                    bh[nt] = *(const bf8_t*)&Bs[0][nr][kb];
                    bm[nt] = *(const bf8_t*)&Bs[1][nr][kb];
                    bl[nt] = *(const bf8_t*)&Bs[2][nr][kb];
                }
#pragma unroll
                for (int mt = 0; mt < 4; ++mt) {
                    const int mr = mw + mt*16 + l16;
                    bf8_t a = *(const bf8_t*)&As[cur][mr][SWZ64(mr, quad + kk*4)];
#pragma unroll
                    for (int nt = 0; nt < 4; ++nt) {
                        f32x4 c = acc[mt][nt];
                        c = MFMA(a, bh[nt], c);
                        c = MFMA(a, bm[nt], c);
                        c = MFMA(a, bl[nt], c);
                        acc[mt][nt] = c;
                    }
                }
            }
            __builtin_amdgcn_s_setprio(0);
            cur ^= 1;
        }

        // fused LIF + weighted sparse scatter
#pragma unroll
        for (int mt = 0; mt < 4; ++mt) {
            const int rbase = m0 + mw + mt*16 + quad*4;
#pragma unroll
            for (int reg = 0; reg < 4; ++reg) {
                const int   n = tok[rbase + reg];
                const float w = wgt[rbase + reg];
#pragma unroll
                for (int nt = 0; nt < 4; ++nt) {
                    float mv = __fadd_rn(__fmul_rn(0.9f, mem[mt][nt][reg]), acc[mt][nt][reg]);
                    bool s = mv > 1.0f;
                    mem[mt][nt][reg] = __fsub_rn(mv, s ? 1.0f : 0.0f);
                    if (s && w != 0.0f) {
                        int col = dt*128 + nw + nt*16 + l16;
                        atomicAdd(out + ((size_t)t * NTOK + n) * DMODEL + col, w);
                    }
                }
            }
        }
    }
}

// ---------------- launch ----------------

extern "C" void kernel_launch(void* const* d_in, const int* in_sizes, int n_in,
                              void* d_out, int out_size, void* d_ws, size_t ws_size,
                              hipStream_t stream) {
    const float* x      = (const float*)d_in[0];
    const int*   idx    = (const int*)  d_in[1];
    const float* wts    = (const float*)d_in[2];
    const float* up_w   = (const float*)d_in[3];
    const float* down_w = (const float*)d_in[4];
    float* out = (float*)d_out;

    char* ws = (char*)d_ws;
    int*   counts  = (int*)(ws + 0);
    int*   cursors = (int*)(ws + 32);
    int*   offsets = (int*)(ws + 64);
    int*   tok     = (int*)(ws + 128);
    float* wgt     = (float*)(ws + 128 + (size_t)CAPTOT * 4);
    unsigned short* spk = (unsigned short*)(ws + 128 + (size_t)CAPTOT * 8);

    const size_t WSPK = (size_t)T_STEPS * CAPTOT * EFF * 2;             // 71.3 MB
    size_t base2 = 128 + (size_t)CAPTOT * 8 + WSPK;
    base2 = (base2 + 511) & ~(size_t)511;
    const size_t WLIMB = (size_t)NEXP * EFF * DMODEL * 2;               // 8.39 MB per limb
    unsigned short* uwh = (unsigned short*)(ws + base2);
    unsigned short* uwm = (unsigned short*)(ws + base2 + 1*WLIMB);
    unsigned short* uwl = (unsigned short*)(ws + base2 + 2*WLIMB);
    unsigned short* dwh = (unsigned short*)(ws + base2 + 3*WLIMB);
    unsigned short* dwm = (unsigned short*)(ws + base2 + 4*WLIMB);
    unsigned short* dwl = (unsigned short*)(ws + base2 + 5*WLIMB);
    // total ws: ~122 MB

    hipMemsetAsync(ws, 0, 128 + (size_t)CAPTOT * 8, stream);
    hipMemsetAsync(out, 0, (size_t)out_size * sizeof(float), stream);

    // one-shot weight limb split: 8 floats/thread, 2048 blocks each
    const int nsplit = NEXP * EFF * DMODEL / 8 / 256;
    k_split<<<nsplit, 256, 0, stream>>>(up_w,   uwh, uwm, uwl);
    k_split<<<nsplit, 256, 0, stream>>>(down_w, dwh, dwm, dwl);

    k_count <<<(NTOK + 255) / 256, 256, 0, stream>>>(idx, counts);
    k_prefix<<<1, 64, 0, stream>>>(counts, offsets);
    k_fill  <<<(NTOK + 255) / 256, 256, 0, stream>>>(idx, wts, offsets, cursors, tok, wgt);

    dim3 gup(CAPTOT / BMT, EFF / 128);      // (136, 4); tiles past used rows early-exit
    k_up<<<gup, 256, 0, stream>>>(x, uwh, uwm, uwl, offsets, tok, spk);

    dim3 gdn(CAPTOT / BMT, DMODEL / 128);   // (136, 8)
    k_dn<<<gdn, 256, 0, stream>>>(spk, dwh, dwm, dwl, offsets, tok, wgt, out);
}

// Round 8
// 903.884 us; speedup vs baseline: 1.3667x; 1.3189x over previous
//
#include <hip/hip_runtime.h>
#include <stdint.h>

#define T_STEPS 4
#define NTOK    8192
#define DMODEL  1024
#define NEXP    8
#define EFF     512
#define BMT     128                      // block tile rows (tokens); expert regions padded to 128
#define CAPTOT  (2*NTOK + NEXP*BMT)      // 17408 assignment slots incl. per-expert padding

typedef __attribute__((ext_vector_type(8))) short bf8_t;   // 8 bf16 (4 VGPRs) MFMA operand
typedef __attribute__((ext_vector_type(4))) float f32x4;   // MFMA accumulator

#define MFMA(a,b,c) __builtin_amdgcn_mfma_f32_16x16x32_bf16((a),(b),(c),0,0,0)

// 32-short (64B) LDS rows: phys_chunk = logical_chunk ^ ((row>>1)&3). Conflict-free (r2-r5).
#define SWZC(r, c)  ((((c) ^ (((r) >> 1) & 3))) * 8)
// 64-short (128B) LDS rows: phys_chunk = logical_chunk ^ (row&7). Reads 2-way (free, m136).
#define SWZ64(r, c) ((((c) ^ ((r) & 7))) * 8)

// async global->LDS DMA, 16B/lane, no VGPR round-trip (vmcnt-tracked)
typedef __attribute__((address_space(3))) unsigned int lds_uint;
typedef const __attribute__((address_space(1))) unsigned int glb_uint;
__device__ __forceinline__ void dma16(const void* g, void* l) {
    __builtin_amdgcn_global_load_lds((glb_uint*)g, (lds_uint*)l, 16, 0, 0);
}
#define S_BARRIER() __builtin_amdgcn_s_barrier()
#define SFENCE()    __builtin_amdgcn_sched_barrier(0)

// Balanced XCD-chunked tile map (r7 lesson / ERRATA#11): partition the USED tiles
// (n_used = offsets[NEXP]/128, known on device) across 8 XCDs, not the padded 136.
// gridDim.x = 136 % 8 == 0 so hardware XCD = bx & 7 for any blockIdx.y. Each XCD gets
// q or q+1 contiguous tiles (~= one expert region -> 3MB weight slice L2-resident;
// FETCH 625->260MB measured r7). Overflow positions -> early-exit tile. With
// n_used=120: 15 tiles/XCD, k_up 60 blocks/XCD <= 64 slots -> ONE dispatch round
// (r7's chunk-17 map put 68 on XCDs 0-6 = two rounds = the 1.56x regression).
__device__ __forceinline__ int bal_tile(int bx, int n_used) {
    const int xcd = bx & 7, pos = bx >> 3;
    const int q = n_used >> 3, rr = n_used & 7;
    const int alloc = q + (xcd < rr ? 1 : 0);
    if (pos >= alloc) return n_used;                       // maps past used -> early-exit
    const int base = (xcd < rr) ? xcd * (q + 1) : rr * (q + 1) + (xcd - rr) * q;
    return base + pos;
}

// ---------------- bf16 3-limb split helpers ----------------

__device__ __forceinline__ unsigned short bf16rn(float f) {
    unsigned u = __float_as_uint(f);
    unsigned r = u + 0x7fffu + ((u >> 16) & 1u);   // round-to-nearest-even
    return (unsigned short)(r >> 16);
}
__device__ __forceinline__ float bf2f(unsigned short h) {
    return __uint_as_float(((unsigned)h) << 16);
}
__device__ __forceinline__ unsigned pk(unsigned short a, unsigned short b) {
    return (unsigned)a | ((unsigned)b << 16);
}

// split 8 floats (in regs) into 3 bf16 limbs, write 16B per limb to LDS
__device__ __forceinline__ void split8v(float4 va, float4 vb,
                                        unsigned short* d0, unsigned short* d1,
                                        unsigned short* d2) {
    float v[8];
    *(float4*)&v[0] = va;
    *(float4*)&v[4] = vb;
    unsigned short h[8], m[8], l[8];
#pragma unroll
    for (int i = 0; i < 8; ++i) {
        unsigned short a = bf16rn(v[i]);
        float r1 = v[i] - bf2f(a);
        unsigned short b = bf16rn(r1);
        float r2 = r1 - bf2f(b);
        h[i] = a; m[i] = b; l[i] = bf16rn(r2);
    }
    *(uint4*)d0 = make_uint4(pk(h[0],h[1]), pk(h[2],h[3]), pk(h[4],h[5]), pk(h[6],h[7]));
    *(uint4*)d1 = make_uint4(pk(m[0],m[1]), pk(m[2],m[3]), pk(m[4],m[5]), pk(m[6],m[7]));
    *(uint4*)d2 = make_uint4(pk(l[0],l[1]), pk(l[2],l[3]), pk(l[4],l[5]), pk(l[6],l[7]));
}

__device__ __forceinline__ void stage8_3limb(const float* __restrict__ src,
                                             unsigned short* d0, unsigned short* d1,
                                             unsigned short* d2) {
    float4 va = *(const float4*)(src + 0);
    float4 vb = *(const float4*)(src + 4);
    split8v(va, vb, d0, d1, d2);
}

// ---------------- weight limb pre-split (one-shot, streaming) ----------------

__global__ void k_split(const float* __restrict__ w, unsigned short* __restrict__ h,
                        unsigned short* __restrict__ m, unsigned short* __restrict__ l) {
    size_t i = (size_t)(blockIdx.x * blockDim.x + threadIdx.x) * 8;
    stage8_3limb(w + i, h + i, m + i, l + i);
}

// ---------------- routing ----------------

__global__ void k_count(const int* __restrict__ idx, int* __restrict__ counts) {
    int n = blockIdx.x * blockDim.x + threadIdx.x;
    if (n >= NTOK) return;
    int e0 = idx[2*n], e1 = idx[2*n+1];
    atomicAdd(&counts[e0], 1);
    if (e1 != e0) atomicAdd(&counts[e1], 1);   // dedup duplicate top-k
}

__global__ void k_prefix(const int* __restrict__ counts, int* __restrict__ offsets) {
    if (threadIdx.x == 0) {
        int o = 0;
        for (int e = 0; e < NEXP; ++e) {
            offsets[e] = o;
            o += (counts[e] + BMT - 1) / BMT * BMT;   // pad each expert region to 128
        }
        offsets[NEXP] = o;
    }
}

__global__ void k_fill(const int* __restrict__ idx, const float* __restrict__ wts,
                       const int* __restrict__ offsets, int* __restrict__ cursors,
                       int* __restrict__ tok, float* __restrict__ wgt) {
    int n = blockIdx.x * blockDim.x + threadIdx.x;
    if (n >= NTOK) return;
    int e0 = idx[2*n], e1 = idx[2*n+1];
    float w0 = wts[2*n], w1 = wts[2*n+1];
    if (e0 == e1) w0 = __fadd_rn(w0, w1);      // reference scatter-add order
    int p0 = offsets[e0] + atomicAdd(&cursors[e0], 1);
    tok[p0] = n; wgt[p0] = w0;
    if (e1 != e0) {
        int p1 = offsets[e1] + atomicAdd(&cursors[e1], 1);
        tok[p1] = n; wgt[p1] = w1;
    }
}

// ---------------- up-proj (3-limb bf16 MFMA) + fused LIF -> bf16 spikes ----------------
// r5-proven schedule (428us): A = f32 reg-prefetch one step ahead + in-kernel limb split
// (split VALU overlaps the pipeline bubble; r5/r6 proved it's not the critical path);
// B = pre-split limbs DMA'd into double-buffered LDS, in flight across barriers with
// counted vmcnt(10). No s_setprio (r7: co-introduced with regression; m190: null-to-neg
// on 2-phase GEMM). Balanced device-side XCD swizzle (see bal_tile).

__global__ __launch_bounds__(256, 2)
void k_up(const float* __restrict__ x,
          const unsigned short* __restrict__ uwh, const unsigned short* __restrict__ uwm,
          const unsigned short* __restrict__ uwl,
          const int* __restrict__ offsets, const int* __restrict__ tok,
          unsigned short* __restrict__ spk) {
    const int n_used = offsets[NEXP] / BMT;
    const int m0 = bal_tile(blockIdx.x, n_used) * BMT;
    const int ft = blockIdx.y;
    if (m0 >= offsets[NEXP]) return;
    int e = 0;
    for (int i = 1; i < NEXP; ++i) if (m0 >= offsets[i]) e = i;

    __shared__ __align__(16) unsigned short As[3][128][32];      // 24 KB, single-buffered
    __shared__ __align__(16) unsigned short Bs[2][3][128][32];   // 48 KB, double-buffered
    // total 72 KB -> 2 blocks/CU

    const int tid  = threadIdx.x;
    const int lane = tid & 63, wid = tid >> 6;
    const int quad = lane >> 4, l16 = lane & 15;
    const int mw = (wid & 1) * 64, nw = (wid >> 1) * 64;

    // A staging roles: thread -> row r (0..127), 16-elem half
    const int r = tid >> 1, half = tid & 1;
    const int c0 = SWZC(r, half*2 + 0);
    const int c1 = SWZC(r, half*2 + 1);
    const int tokA = tok[m0 + r];
    const float* xbase = x + (size_t)tokA * DMODEL + half * 16;

    // B DMA roles: lane l -> row rh*64+wid*16+(l>>2), phys chunk l&3; source fetches
    // logical chunk (l&3)^((l>>3)&3) so linear LDS dest ends up SWZC-swizzled.
    const unsigned short* wlimb[3] = { uwh, uwm, uwl };
    const size_t wrow0 = ((size_t)e * EFF + ft * 128) * DMODEL;
    const int drow  = lane >> 2;
    const int dclog = (lane & 3) ^ ((lane >> 3) & 3);

    // frag-read k-chunk (uniform across mt/nt)
    const int kq = SWZC(l16, quad);

    f32x4 mem[4][4];
#pragma unroll
    for (int i = 0; i < 4; ++i)
#pragma unroll
        for (int j = 0; j < 4; ++j) mem[i][j] = (f32x4){0.f,0.f,0.f,0.f};

    // prologue: DMA B(step 0) into Bs[0]; load A(step 0) into regs
#pragma unroll
    for (int j = 0; j < 6; ++j) {
        const int limb = j >> 1, rh = j & 1;
        dma16(wlimb[limb] + wrow0 + (size_t)(rh*64 + wid*16 + drow) * DMODEL + dclog*8,
              &Bs[0][limb][rh*64 + wid*16][0]);
    }
    float4 pa[4];
#pragma unroll
    for (int i = 0; i < 4; ++i) pa[i] = ((const float4*)xbase)[i];

    int cur = 0;
    for (int t = 0; t < T_STEPS; ++t) {
        f32x4 acc[4][4];
#pragma unroll
        for (int i = 0; i < 4; ++i)
#pragma unroll
            for (int j = 0; j < 4; ++j) acc[i][j] = (f32x4){0.f,0.f,0.f,0.f};

        const float* xrow = xbase + (size_t)t * NTOK * DMODEL;

        for (int kc = 0; kc < DMODEL; kc += 32) {
            const bool last = (t == T_STEPS - 1) && (kc == DMODEL - 32);
            // (W): all waves done reading As / Bs[cur^1]
            asm volatile("s_waitcnt lgkmcnt(0)" ::: "memory");
            SFENCE();
            S_BARRIER();
            SFENCE();
            // next-step B DMA into the freed buffer (stays in flight all step)
            if (!last) {
                const int nkk = (kc == DMODEL - 32) ? 0 : kc + 32;   // B is t-independent
#pragma unroll
                for (int j = 0; j < 6; ++j) {
                    const int limb = j >> 1, rh = j & 1;
                    dma16(wlimb[limb] + wrow0 + (size_t)(rh*64 + wid*16 + drow) * DMODEL
                              + nkk + dclog*8,
                          &Bs[cur ^ 1][limb][rh*64 + wid*16][0]);
                }
            }
            // stage A (consumes pa; DMAs stay in flight)
            split8v(pa[0], pa[1], &As[0][r][c0], &As[1][r][c0], &As[2][r][c0]);
            split8v(pa[2], pa[3], &As[0][r][c1], &As[1][r][c1], &As[2][r][c1]);
            // issue next-step A loads
            if (!last) {
                const float* nxtA = (kc == DMODEL - 32)
                    ? xbase + (size_t)(t + 1) * NTOK * DMODEL
                    : xrow + kc + 32;
#pragma unroll
                for (int i = 0; i < 4; ++i) pa[i] = ((const float4*)nxtA)[i];
                // B(cur) done when <=10 newer ops (6 B-DMA + 4 A-loads) outstanding
                asm volatile("s_waitcnt vmcnt(10) lgkmcnt(0)" ::: "memory");
            } else {
                asm volatile("s_waitcnt vmcnt(0) lgkmcnt(0)" ::: "memory");
            }
            SFENCE();
            S_BARRIER();   // (R): every wave passed its counted wait -> B(cur)+As ready
            SFENCE();

            bf8_t bh[4], bm[4], bl[4];
#pragma unroll
            for (int nt = 0; nt < 4; ++nt) {
                const int nr = nw + nt*16 + l16;
                bh[nt] = *(const bf8_t*)&Bs[cur][0][nr][kq];
                bm[nt] = *(const bf8_t*)&Bs[cur][1][nr][kq];
                bl[nt] = *(const bf8_t*)&Bs[cur][2][nr][kq];
            }
#pragma unroll
            for (int mt = 0; mt < 4; ++mt) {
                const int mr = mw + mt*16 + l16;
                bf8_t ah = *(const bf8_t*)&As[0][mr][kq];
                bf8_t am = *(const bf8_t*)&As[1][mr][kq];
                bf8_t al = *(const bf8_t*)&As[2][mr][kq];
#pragma unroll
                for (int nt = 0; nt < 4; ++nt) {
                    f32x4 c = acc[mt][nt];
                    c = MFMA(ah, bh[nt], c);
                    c = MFMA(am, bh[nt], c);
                    c = MFMA(ah, bm[nt], c);
                    c = MFMA(am, bm[nt], c);
                    c = MFMA(al, bh[nt], c);
                    c = MFMA(ah, bl[nt], c);
                    acc[mt][nt] = c;
                }
            }
            cur ^= 1;
        }

        // fused LIF epilogue (C layout: row = quad*4+reg, col = l16)
#pragma unroll
        for (int mt = 0; mt < 4; ++mt)
#pragma unroll
            for (int nt = 0; nt < 4; ++nt)
#pragma unroll
                for (int reg = 0; reg < 4; ++reg) {
                    float mv = __fadd_rn(__fmul_rn(0.9f, mem[mt][nt][reg]), acc[mt][nt][reg]);
                    bool s = mv > 1.0f;
                    mem[mt][nt][reg] = __fsub_rn(mv, s ? 1.0f : 0.0f);
                    int row = m0 + mw + mt*16 + quad*4 + reg;
                    int col = ft*128 + nw + nt*16 + l16;
                    spk[((size_t)t * CAPTOT + row) * EFF + col] = s ? 0x3F80u : 0u;
                }
    }
}

// ---------------- down-proj (spikes x pre-split 3-limb weights) + fused LIF + scatter ----------------
// BK=64: 32 barrier-pairs per block, 96 MFMA/wave/step. As double-buffered (spikes,
// prefetched 1 step ahead); Bs single-buffered, DMA'd in-step (L2-resident under the
// balanced swizzle). 80KB LDS = 2 blocks/CU. Bit-exact K/limb order.

__global__ __launch_bounds__(256, 2)
void k_dn(const unsigned short* __restrict__ spk,
          const unsigned short* __restrict__ dwh, const unsigned short* __restrict__ dwm,
          const unsigned short* __restrict__ dwl,
          const int* __restrict__ offsets, const int* __restrict__ tok,
          const float* __restrict__ wgt, float* __restrict__ out) {
    const int n_used = offsets[NEXP] / BMT;
    const int m0 = bal_tile(blockIdx.x, n_used) * BMT;
    const int dt = blockIdx.y;
    if (m0 >= offsets[NEXP]) return;
    int e = 0;
    for (int i = 1; i < NEXP; ++i) if (m0 >= offsets[i]) e = i;

    __shared__ __align__(16) unsigned short As[2][128][64];   // 32 KB spikes, double-buffered
    __shared__ __align__(16) unsigned short Bs[3][128][64];   // 48 KB weights, single-buffered

    const int tid  = threadIdx.x;
    const int lane = tid & 63, wid = tid >> 6;
    const int quad = lane >> 4, l16 = lane & 15;
    const int mw = (wid & 1) * 64, nw = (wid >> 1) * 64;

    const unsigned short* dlimb[3] = { dwh, dwm, dwl };
    const size_t drow0 = ((size_t)e * DMODEL + dt * 128) * EFF;
    // DMA roles (128B rows): one dma16 = 1024B = 8 rows; lane l -> row +(l>>3),
    // phys chunk l&7; source logical chunk (l&7)^((l>>3)&7) -> SWZ64 layout in LDS.
    const int drow8 = lane >> 3;
    const int dclog = (lane & 7) ^ ((lane >> 3) & 7);

    f32x4 mem[4][4];
#pragma unroll
    for (int i = 0; i < 4; ++i)
#pragma unroll
        for (int j = 0; j < 4; ++j) mem[i][j] = (f32x4){0.f,0.f,0.f,0.f};

    // prologue: A(step 0) prefetch; rows wave-partitioned (wave w: rows w*32..w*32+31)
#pragma unroll
    for (int j2 = 0; j2 < 4; ++j2) {
        const int rowb = wid*32 + j2*8;
        dma16(spk + ((size_t)(m0 + rowb + drow8)) * EFF + dclog*8,
              &As[0][rowb][0]);
    }

    int cur = 0;
    for (int t = 0; t < T_STEPS; ++t) {
        f32x4 acc[4][4];
#pragma unroll
        for (int i = 0; i < 4; ++i)
#pragma unroll
            for (int j = 0; j < 4; ++j) acc[i][j] = (f32x4){0.f,0.f,0.f,0.f};

        for (int kc = 0; kc < EFF; kc += 64) {
            const bool last = (t == T_STEPS - 1) && (kc == EFF - 64);
            // (W): all waves done reading Bs(prev) and As[cur^1](prev step)
            asm volatile("s_waitcnt lgkmcnt(0)" ::: "memory");
            SFENCE();
            S_BARRIER();
            SFENCE();
            // B(this step): in-step DMA, L2-resident (12 issues/wave)
#pragma unroll
            for (int limb = 0; limb < 3; ++limb)
#pragma unroll
                for (int j2 = 0; j2 < 4; ++j2) {
                    const int rowb = wid*32 + j2*8;
                    dma16(dlimb[limb] + drow0 + (size_t)(rowb + drow8) * EFF + kc + dclog*8,
                          &Bs[limb][rowb][0]);
                }
            // A(next step) prefetch into the freed buffer (4 issues/wave)
            if (!last) {
                int ntt = t, nkk = kc + 64;
                if (nkk == EFF) { nkk = 0; ntt = t + 1; }
#pragma unroll
                for (int j2 = 0; j2 < 4; ++j2) {
                    const int rowb = wid*32 + j2*8;
                    dma16(spk + ((size_t)ntt * CAPTOT + m0 + rowb + drow8) * EFF + nkk + dclog*8,
                          &As[cur ^ 1][rowb][0]);
                }
                // A(cur)+B(cur) done when <=4 newer (next-A) outstanding
                asm volatile("s_waitcnt vmcnt(4)" ::: "memory");
            } else {
                asm volatile("s_waitcnt vmcnt(0)" ::: "memory");
            }
            SFENCE();
            S_BARRIER();   // (R)
            SFENCE();

#pragma unroll
            for (int kk = 0; kk < 2; ++kk) {
                bf8_t bh[4], bm[4], bl[4];
#pragma unroll
                for (int nt = 0; nt < 4; ++nt) {
                    const int nr = nw + nt*16 + l16;
                    const int kb = SWZ64(nr, quad + kk*4);
                    bh[nt] = *(const bf8_t*)&Bs[0][nr][kb];
                    bm[nt] = *(const bf8_t*)&Bs[1][nr][kb];
                    bl[nt] = *(const bf8_t*)&Bs[2][nr][kb];
                }
#pragma unroll
                for (int mt = 0; mt < 4; ++mt) {
                    const int mr = mw + mt*16 + l16;
                    bf8_t a = *(const bf8_t*)&As[cur][mr][SWZ64(mr, quad + kk*4)];
#pragma unroll
                    for (int nt = 0; nt < 4; ++nt) {
                        f32x4 c = acc[mt][nt];
                        c = MFMA(a, bh[nt], c);
                        c = MFMA(a, bm[nt], c);
                        c = MFMA(a, bl[nt], c);
                        acc[mt][nt] = c;
                    }
                }
            }
            cur ^= 1;
        }

        // fused LIF + weighted sparse scatter
#pragma unroll
        for (int mt = 0; mt < 4; ++mt) {
            const int rbase = m0 + mw + mt*16 + quad*4;
#pragma unroll
            for (int reg = 0; reg < 4; ++reg) {
                const int   n = tok[rbase + reg];
                const float w = wgt[rbase + reg];
#pragma unroll
                for (int nt = 0; nt < 4; ++nt) {
                    float mv = __fadd_rn(__fmul_rn(0.9f, mem[mt][nt][reg]), acc[mt][nt][reg]);
                    bool s = mv > 1.0f;
                    mem[mt][nt][reg] = __fsub_rn(mv, s ? 1.0f : 0.0f);
                    if (s && w != 0.0f) {
                        int col = dt*128 + nw + nt*16 + l16;
                        atomicAdd(out + ((size_t)t * NTOK + n) * DMODEL + col, w);
                    }
                }
            }
        }
    }
}

// ---------------- launch ----------------

extern "C" void kernel_launch(void* const* d_in, const int* in_sizes, int n_in,
                              void* d_out, int out_size, void* d_ws, size_t ws_size,
                              hipStream_t stream) {
    const float* x      = (const float*)d_in[0];
    const int*   idx    = (const int*)  d_in[1];
    const float* wts    = (const float*)d_in[2];
    const float* up_w   = (const float*)d_in[3];
    const float* down_w = (const float*)d_in[4];
    float* out = (float*)d_out;

    char* ws = (char*)d_ws;
    int*   counts  = (int*)(ws + 0);
    int*   cursors = (int*)(ws + 32);
    int*   offsets = (int*)(ws + 64);
    int*   tok     = (int*)(ws + 128);
    float* wgt     = (float*)(ws + 128 + (size_t)CAPTOT * 4);
    unsigned short* spk = (unsigned short*)(ws + 128 + (size_t)CAPTOT * 8);

    const size_t WSPK = (size_t)T_STEPS * CAPTOT * EFF * 2;             // 71.3 MB
    size_t base2 = 128 + (size_t)CAPTOT * 8 + WSPK;
    base2 = (base2 + 511) & ~(size_t)511;
    const size_t WLIMB = (size_t)NEXP * EFF * DMODEL * 2;               // 8.39 MB per limb
    unsigned short* uwh = (unsigned short*)(ws + base2);
    unsigned short* uwm = (unsigned short*)(ws + base2 + 1*WLIMB);
    unsigned short* uwl = (unsigned short*)(ws + base2 + 2*WLIMB);
    unsigned short* dwh = (unsigned short*)(ws + base2 + 3*WLIMB);
    unsigned short* dwm = (unsigned short*)(ws + base2 + 4*WLIMB);
    unsigned short* dwl = (unsigned short*)(ws + base2 + 5*WLIMB);
    // total ws: ~122 MB

    hipMemsetAsync(ws, 0, 128 + (size_t)CAPTOT * 8, stream);
    hipMemsetAsync(out, 0, (size_t)out_size * sizeof(float), stream);

    // one-shot weight limb split: 8 floats/thread, 2048 blocks each
    const int nsplit = NEXP * EFF * DMODEL / 8 / 256;
    k_split<<<nsplit, 256, 0, stream>>>(up_w,   uwh, uwm, uwl);
    k_split<<<nsplit, 256, 0, stream>>>(down_w, dwh, dwm, dwl);

    k_count <<<(NTOK + 255) / 256, 256, 0, stream>>>(idx, counts);
    k_prefix<<<1, 64, 0, stream>>>(counts, offsets);
    k_fill  <<<(NTOK + 255) / 256, 256, 0, stream>>>(idx, wts, offsets, cursors, tok, wgt);

    dim3 gup(CAPTOT / BMT, EFF / 128);      // (136, 4); 136%8==0 keeps XCD = bx&7
    k_up<<<gup, 256, 0, stream>>>(x, uwh, uwm, uwl, offsets, tok, spk);

    dim3 gdn(CAPTOT / BMT, DMODEL / 128);   // (136, 8)
    k_dn<<<gdn, 256, 0, stream>>>(spk, dwh, dwm, dwl, offsets, tok, wgt, out);
}